// Round 13
// baseline (4726.870 us; speedup 1.0000x reference)
//
#include <hip/hip_runtime.h>
#include <stdint.h>

#define NN 4096
#define BB 4
#define MROWS 16        // rows per block
#define TPB 1024        // 16 waves
#define NBLK 256        // grid (1 block/CU)
#define REDS 17         // padded red row stride (dwords)

#define ROOT_OFF 256    // dword index of root counter in cnt buffer
#define REL_OFF  288    // dword index of release-epoch flag

typedef __attribute__((ext_vector_type(8))) short bf16x8;   // 8 bf16 (4 VGPRs)
typedef __attribute__((ext_vector_type(4))) float f32x4;    // MFMA C/D

// ---------- bf16 round-to-nearest-even ----------
__device__ __forceinline__ uint32_t bf16rne(float f) {
  uint32_t u = __float_as_uint(f);
  return (u + 0x7FFFu + ((u >> 16) & 1u)) >> 16;
}

// ---------- pack B fp32 -> two row-major bf16 planes (32 MB each) ----------
__global__ void pack_planes(const float* __restrict__ Br, const float* __restrict__ Bi,
                            uint4* __restrict__ Brb, uint4* __restrict__ Bib) {
  int i = blockIdx.x * blockDim.x + threadIdx.x;     // over N*N/8
  const float4* r4 = reinterpret_cast<const float4*>(Br) + (size_t)i * 2;
  const float4* m4 = reinterpret_cast<const float4*>(Bi) + (size_t)i * 2;
  float4 a0 = r4[0], a1 = r4[1];
  float4 b0 = m4[0], b1 = m4[1];
  uint4 o;
  o.x = bf16rne(a0.x) | (bf16rne(a0.y) << 16);
  o.y = bf16rne(a0.z) | (bf16rne(a0.w) << 16);
  o.z = bf16rne(a1.x) | (bf16rne(a1.y) << 16);
  o.w = bf16rne(a1.z) | (bf16rne(a1.w) << 16);
  Brb[i] = o;
  o.x = bf16rne(b0.x) | (bf16rne(b0.y) << 16);
  o.y = bf16rne(b0.z) | (bf16rne(b0.w) << 16);
  o.z = bf16rne(b1.x) | (bf16rne(b1.y) << 16);
  o.w = bf16rne(b1.z) | (bf16rne(b1.w) << 16);
  Bib[i] = o;
}

// ---------- hierarchical grid barrier, value-based epoch e = 1,2,3,... ----------
// 8 group counters (one per XCD via blockIdx&7, 128B apart) -> root -> release flag.
// Release-sequence chain: block(REL on grp) -> group-last(ACQ_REL grp, REL root)
// -> root-last(ACQ_REL root, REL rel) -> pollers(ACQ rel).
__device__ __forceinline__ void gbar(uint32_t* cnt, uint32_t e) {
  __syncthreads();                     // drain block's stores (vmcnt0) + block barrier
  if (threadIdx.x == 0) {
    const int g = blockIdx.x & 7;
    uint32_t old = __hip_atomic_fetch_add(&cnt[g * 32], 1u,
                                          __ATOMIC_ACQ_REL, __HIP_MEMORY_SCOPE_AGENT);
    if (old == 32u * e - 1u) {         // last of this group for epoch e
      uint32_t r = __hip_atomic_fetch_add(&cnt[ROOT_OFF], 1u,
                                          __ATOMIC_ACQ_REL, __HIP_MEMORY_SCOPE_AGENT);
      if (r == 8u * e - 1u) {          // last group overall
        __hip_atomic_store(&cnt[REL_OFF], e, __ATOMIC_RELEASE, __HIP_MEMORY_SCOPE_AGENT);
      }
    }
    while (__hip_atomic_load(&cnt[REL_OFF], __ATOMIC_RELAXED,
                             __HIP_MEMORY_SCOPE_AGENT) < e) {
      __builtin_amdgcn_s_sleep(2);
    }
    (void)__hip_atomic_load(&cnt[REL_OFF], __ATOMIC_ACQUIRE, __HIP_MEMORY_SCOPE_AGENT);
  }
  __syncthreads();
}

// ============================================================================
// Persistent kernel: all steps in one launch; B bf16 fragments pinned in VGPRs
// via opaque asm (defeats remat-by-reload across the barrier fences).
// x state: flat bf16 planes xbuf[buf][plane c=2b+ri][node n], double-buffered.
// Fragment maps identical to rounds 10-12 (verified, absmax 0.0039).
// ============================================================================
__global__ __launch_bounds__(TPB, 4)   // 4 waves/SIMD -> 128-VGPR cap
void rnn_persistent(const uint16_t* __restrict__ Brb,
                    const uint16_t* __restrict__ Bib,
                    const float* __restrict__ omega,
                    const float* __restrict__ ang,
                    uint16_t* __restrict__ xbuf,   // 2 * 8*NN bf16
                    uint32_t* __restrict__ cnt,    // barrier counters (zeroed)
                    float* __restrict__ out,
                    int NT) {
  __shared__ float red[16 * 16 * REDS];            // 17408 B

  const int tid  = threadIdx.x;
  const int w    = tid >> 6;
  const int lane = tid & 63;
  const int al   = lane & 15;
  const int kq   = lane >> 4;
  const int row0 = blockIdx.x * MROWS;
  const int p1   = al & 7;
  const int p2   = p1 ^ 1;
  const uint64_t sm64 = (al & 1) ? 0ull : 0x8000800080008000ull;  // negate -xi (even cols)

  // ---- load B fragments into registers (once) ----
  const uint16_t* arow = Brb + (size_t)(row0 + al) * NN + w * 256 + kq * 8;
  const uint16_t* brow = Bib + (size_t)(row0 + al) * NN + w * 256 + kq * 8;
  bf16x8 aR0 = *(const bf16x8*)(arow +   0), aI0 = *(const bf16x8*)(brow +   0);
  bf16x8 aR1 = *(const bf16x8*)(arow +  32), aI1 = *(const bf16x8*)(brow +  32);
  bf16x8 aR2 = *(const bf16x8*)(arow +  64), aI2 = *(const bf16x8*)(brow +  64);
  bf16x8 aR3 = *(const bf16x8*)(arow +  96), aI3 = *(const bf16x8*)(brow +  96);
  bf16x8 aR4 = *(const bf16x8*)(arow + 128), aI4 = *(const bf16x8*)(brow + 128);
  bf16x8 aR5 = *(const bf16x8*)(arow + 160), aI5 = *(const bf16x8*)(brow + 160);
  bf16x8 aR6 = *(const bf16x8*)(arow + 192), aI6 = *(const bf16x8*)(brow + 192);
  bf16x8 aR7 = *(const bf16x8*)(arow + 224), aI7 = *(const bf16x8*)(brow + 224);

  // ---- pin fragments: defs become opaque asm outputs -> cannot be re-loaded ----
  asm volatile("" : "+v"(aR0), "+v"(aR1), "+v"(aR2), "+v"(aR3),
                    "+v"(aR4), "+v"(aR5), "+v"(aR6), "+v"(aR7),
                    "+v"(aI0), "+v"(aI1), "+v"(aI2), "+v"(aI3),
                    "+v"(aI4), "+v"(aI5), "+v"(aI6), "+v"(aI7));

  // ---- t=0: x0 = exp(i*theta); diag regs; out[0]; xbuf buffer 0 ----
  float myval = 0.f, om = 0.f;
  int bb = 0, mm = 0, ri = 0, cc = 0;
  if (tid < 128) {
    int r = tid >> 3; cc = tid & 7;
    mm = row0 + r; bb = cc >> 1; ri = cc & 1;
    om = omega[bb * NN + mm];
    float sv, cv;
    sincosf(ang[bb * NN + mm], &sv, &cv);
    myval = ri ? sv : cv;
    if (!ri) out[bb * NN + mm] = myval;
    xbuf[cc * NN + mm] = (uint16_t)bf16rne(myval);
  }
  gbar(cnt, 1u);                                   // epoch 1

  const int nb = w * 256 + kq * 8;                 // this lane's k-window base

  for (int t = 1; t < NT; ++t) {
    const uint16_t* xs = xbuf + (size_t)((t - 1) & 1) * (8 * NN);
    f32x4 accA = {0.f, 0.f, 0.f, 0.f};
    f32x4 accB = {0.f, 0.f, 0.f, 0.f};

#define SSTEP(S, AR, AI)                                                        \
    { const uint16_t* x1p = xs + p1 * NN + nb + S * 32;                         \
      const uint16_t* x2p = xs + p2 * NN + nb + S * 32;                         \
      union { uint64_t q[2]; bf16x8 v; } u1, u2;                                \
      u1.q[0] = *(const uint64_t*)(x1p);                                        \
      u1.q[1] = *(const uint64_t*)(x1p + 4);                                    \
      u2.q[0] = *(const uint64_t*)(x2p) ^ sm64;                                 \
      u2.q[1] = *(const uint64_t*)(x2p + 4) ^ sm64;                             \
      accA = __builtin_amdgcn_mfma_f32_16x16x32_bf16(AR, u1.v, accA, 0, 0, 0);  \
      accB = __builtin_amdgcn_mfma_f32_16x16x32_bf16(AI, u2.v, accB, 0, 0, 0); }
    SSTEP(0, aR0, aI0) SSTEP(1, aR1, aI1) SSTEP(2, aR2, aI2) SSTEP(3, aR3, aI3)
    SSTEP(4, aR4, aI4) SSTEP(5, aR5, aI5) SSTEP(6, aR6, aI6) SSTEP(7, aR7, aI7)
#undef SSTEP

    // ---- partial tiles -> padded LDS ----
    {
      float* rw = red + w * 16 * REDS;
      rw[(kq * 4 + 0) * REDS + al] = accA[0] + accB[0];
      rw[(kq * 4 + 1) * REDS + al] = accA[1] + accB[1];
      rw[(kq * 4 + 2) * REDS + al] = accA[2] + accB[2];
      rw[(kq * 4 + 3) * REDS + al] = accA[3] + accB[3];
    }
    __syncthreads();

    // ---- cross-wave sum + diagonal + writes ----
    if (tid < 128) {
      int r = tid >> 3;
      float s = 0.f;
#pragma unroll
      for (int w2 = 0; w2 < 16; ++w2) s += red[w2 * 16 * REDS + r * REDS + cc];
      float other = __shfl_xor(myval, 1, 64);
      float xr = ri ? other : myval;
      float xi = ri ? myval : other;
      // i*omega*(xr + i*xi) = -omega*xi + i*omega*xr
      s += ri ? (om * xr) : (-om * xi);
      myval = s;                                   // fp32 diag chain stays in reg
      if (!ri) out[(size_t)t * (BB * NN) + bb * NN + mm] = s;
      xbuf[(size_t)(t & 1) * (8 * NN) + cc * NN + mm] = (uint16_t)bf16rne(s);
    }

    if (t < NT - 1) gbar(cnt, (uint32_t)(t + 1));  // epoch t+1
  }
}

// ============================================================================
// Fallback (fp32 B direct, per-step launches) — only if coop launch fails.
// ============================================================================
__global__ void init_kernel(const float* __restrict__ ang,
                            float2* __restrict__ st0, float* __restrict__ out0) {
  int i = blockIdx.x * blockDim.x + threadIdx.x;
  if (i < BB * NN) {
    float s, c;
    sincosf(ang[i], &s, &c);
    st0[i] = make_float2(c, s);
    out0[i] = c;
  }
}

__global__ __launch_bounds__(TPB)
void step_fb(const float* __restrict__ Brf, const float* __restrict__ Bif,
             const float* __restrict__ omega,
             const float2* __restrict__ stPrev, float2* __restrict__ stNext,
             float* __restrict__ outRe) {
  extern __shared__ float lds[];
  float* xl  = lds;
  float* xh  = lds + NN * 4;
  float* red = lds + NN * 8;
  const int tid = threadIdx.x;
#pragma unroll
  for (int k = 0; k < 8; ++k) {
    int idx = tid + k * TPB;
    int half = idx >> 12;
    int n = idx & (NN - 1);
    float2 v0 = stPrev[(half * 2) * NN + n];
    float2 v1 = stPrev[(half * 2 + 1) * NN + n];
    reinterpret_cast<float4*>(half ? xh : xl)[n] = make_float4(v0.x, v0.y, v1.x, v1.y);
  }
  __syncthreads();
  const int w = tid >> 6, lane = tid & 63, rg = w >> 2, q = w & 3;
  const int row0 = blockIdx.x * MROWS + rg * 4;
  float acc[4][8];
#pragma unroll
  for (int r = 0; r < 4; ++r)
#pragma unroll
    for (int c = 0; c < 8; ++c) acc[r][c] = 0.0f;
#define CFMA(A, BR, BI, XA, XB)                                   \
  A[0] = fmaf(BR, XA.x, A[0]); A[0] = fmaf(-BI, XA.y, A[0]);      \
  A[1] = fmaf(BR, XA.y, A[1]); A[1] = fmaf(BI, XA.x, A[1]);       \
  A[2] = fmaf(BR, XA.z, A[2]); A[2] = fmaf(-BI, XA.w, A[2]);      \
  A[3] = fmaf(BR, XA.w, A[3]); A[3] = fmaf(BI, XA.z, A[3]);       \
  A[4] = fmaf(BR, XB.x, A[4]); A[4] = fmaf(-BI, XB.y, A[4]);      \
  A[5] = fmaf(BR, XB.y, A[5]); A[5] = fmaf(BI, XB.x, A[5]);       \
  A[6] = fmaf(BR, XB.z, A[6]); A[6] = fmaf(-BI, XB.w, A[6]);      \
  A[7] = fmaf(BR, XB.w, A[7]); A[7] = fmaf(BI, XB.z, A[7]);
  for (int i4 = 0; i4 < 4; ++i4) {
    const int n0 = q * 1024 + i4 * 256 + lane * 4;
    float4 xa[4], xb[4];
#pragma unroll
    for (int j = 0; j < 4; ++j) {
      xa[j] = reinterpret_cast<const float4*>(xl)[n0 + j];
      xb[j] = reinterpret_cast<const float4*>(xh)[n0 + j];
    }
#pragma unroll
    for (int r = 0; r < 4; ++r) {
      const float4 pvr = reinterpret_cast<const float4*>(Brf + (size_t)(row0 + r) * NN)[q * 256 + i4 * 64 + lane];
      const float4 pvi = reinterpret_cast<const float4*>(Bif + (size_t)(row0 + r) * NN)[q * 256 + i4 * 64 + lane];
      float* a = acc[r];
      CFMA(a, pvr.x, pvi.x, xa[0], xb[0]);
      CFMA(a, pvr.y, pvi.y, xa[1], xb[1]);
      CFMA(a, pvr.z, pvi.z, xa[2], xb[2]);
      CFMA(a, pvr.w, pvi.w, xa[3], xb[3]);
    }
  }
#undef CFMA
  float t0 = acc[0][0], t1 = acc[0][1], t2 = acc[0][2], t3 = acc[0][3];
  float t4 = acc[0][4], t5 = acc[0][5], t6 = acc[0][6], t7 = acc[0][7];
  float t8 = acc[1][0], t9 = acc[1][1], t10 = acc[1][2], t11 = acc[1][3];
  float t12 = acc[1][4], t13 = acc[1][5], t14 = acc[1][6], t15 = acc[1][7];
  float t16 = acc[2][0], t17 = acc[2][1], t18 = acc[2][2], t19 = acc[2][3];
  float t20 = acc[2][4], t21 = acc[2][5], t22 = acc[2][6], t23 = acc[2][7];
  float t24 = acc[3][0], t25 = acc[3][1], t26 = acc[3][2], t27 = acc[3][3];
  float t28 = acc[3][4], t29 = acc[3][5], t30 = acc[3][6], t31 = acc[3][7];
#define RSTEP(LO, HI, M)                                          \
  { float s_ = up ? LO : HI;                                      \
    s_ = __shfl_xor(s_, M, 64);                                   \
    LO = (up ? HI : LO) + s_; }
  { const bool up = (lane & 32) != 0;
    RSTEP(t0, t16, 32)  RSTEP(t1, t17, 32)  RSTEP(t2, t18, 32)  RSTEP(t3, t19, 32)
    RSTEP(t4, t20, 32)  RSTEP(t5, t21, 32)  RSTEP(t6, t22, 32)  RSTEP(t7, t23, 32)
    RSTEP(t8, t24, 32)  RSTEP(t9, t25, 32)  RSTEP(t10, t26, 32) RSTEP(t11, t27, 32)
    RSTEP(t12, t28, 32) RSTEP(t13, t29, 32) RSTEP(t14, t30, 32) RSTEP(t15, t31, 32) }
  { const bool up = (lane & 16) != 0;
    RSTEP(t0, t8, 16)  RSTEP(t1, t9, 16)  RSTEP(t2, t10, 16) RSTEP(t3, t11, 16)
    RSTEP(t4, t12, 16) RSTEP(t5, t13, 16) RSTEP(t6, t14, 16) RSTEP(t7, t15, 16) }
  { const bool up = (lane & 8) != 0;
    RSTEP(t0, t4, 8) RSTEP(t1, t5, 8) RSTEP(t2, t6, 8) RSTEP(t3, t7, 8) }
  { const bool up = (lane & 4) != 0;
    RSTEP(t0, t2, 4) RSTEP(t1, t3, 4) }
  { const bool up = (lane & 2) != 0;
    RSTEP(t0, t1, 2) }
#undef RSTEP
  t0 += __shfl_xor(t0, 1, 64);
  if (!(lane & 1)) red[w * 32 + ((lane >> 1) & 31)] = t0;
  __syncthreads();
  if (tid < 128) {
    int rg2 = tid >> 5, v = tid & 31;
    float s = red[(rg2 * 4 + 0) * 32 + v] + red[(rg2 * 4 + 1) * 32 + v] +
              red[(rg2 * 4 + 2) * 32 + v] + red[(rg2 * 4 + 3) * 32 + v];
    int r = v >> 3, c = v & 7, b = c >> 1, ri = c & 1;
    int m = blockIdx.x * MROWS + rg2 * 4 + r;
    float om = omega[b * NN + m];
    const float* xs = (b < 2) ? xl : xh;
    float xr = xs[m * 4 + (b & 1) * 2];
    float xi = xs[m * 4 + (b & 1) * 2 + 1];
    s += (ri == 0) ? (-om * xi) : (om * xr);
    reinterpret_cast<float*>(stNext)[(b * NN + m) * 2 + ri] = s;
    if (ri == 0) outRe[b * NN + m] = s;
  }
}

// ---------- host ----------
extern "C" void kernel_launch(void* const* d_in, const int* in_sizes, int n_in,
                              void* d_out, int out_size, void* d_ws, size_t ws_size,
                              hipStream_t stream) {
  const float* B_real = (const float*)d_in[0];
  const float* B_imag = (const float*)d_in[1];
  const float* omega  = (const float*)d_in[2];
  const float* ang    = (const float*)d_in[3];
  float* out = (float*)d_out;

  int NT = out_size / (BB * NN);                                 // 256
  const size_t planeBytes = (size_t)NN * NN * 2;                 // 32 MB
  const size_t xbufBytes  = (size_t)2 * 8 * NN * 2;              // 128 KB
  const size_t cntBytes   = 4096;                                // barrier lines
  const bool coop = ws_size >= 2 * planeBytes + xbufBytes + cntBytes;

  hipError_t launched = hipErrorUnknown;
  if (coop) {
    uint16_t* Brb = (uint16_t*)d_ws;
    uint16_t* Bib = Brb + (size_t)NN * NN;
    uint16_t* xbuf = (uint16_t*)((char*)d_ws + 2 * planeBytes);
    uint32_t* cnt  = (uint32_t*)((char*)d_ws + 2 * planeBytes + xbufBytes);

    (void)hipMemsetAsync((void*)cnt, 0, cntBytes, stream);       // counters -> 0
    pack_planes<<<NN * NN / 8 / 256, 256, 0, stream>>>(B_real, B_imag,
                                                       (uint4*)Brb, (uint4*)Bib);

    void* kargs[8];
    kargs[0] = (void*)&Brb;
    kargs[1] = (void*)&Bib;
    kargs[2] = (void*)&omega;
    kargs[3] = (void*)&ang;
    kargs[4] = (void*)&xbuf;
    kargs[5] = (void*)&cnt;
    kargs[6] = (void*)&out;
    kargs[7] = (void*)&NT;
    launched = hipLaunchCooperativeKernel((const void*)&rnn_persistent,
                                          dim3(NBLK), dim3(TPB),
                                          kargs, 0, stream);
  }

  if (launched != hipSuccess) {
    // fallback: per-step launches, fp32 B from inputs, state ping-pong in ws
    float2* st0 = (float2*)d_ws;
    float2* st1 = st0 + BB * NN;
    const size_t shmemF = (size_t)(NN * 8 + 16 * 32) * sizeof(float);
    (void)hipFuncSetAttribute((const void*)&step_fb,
                              hipFuncAttributeMaxDynamicSharedMemorySize, (int)shmemF);
    init_kernel<<<(BB * NN + 255) / 256, 256, 0, stream>>>(ang, st0, out);
    for (int t = 1; t < NT; ++t) {
      float2* sp = ((t - 1) & 1) ? st1 : st0;
      float2* sn = (t & 1) ? st1 : st0;
      float* outT = out + (size_t)t * BB * NN;
      step_fb<<<NN / MROWS, TPB, shmemF, stream>>>(B_real, B_imag, omega, sp, sn, outT);
    }
  }
}

// Round 14
// 4438.212 us; speedup vs baseline: 1.0650x; 1.0650x over previous
//
#include <hip/hip_runtime.h>
#include <stdint.h>

#define NN 4096
#define BB 4
#define MROWS 16        // rows per block
#define TPB 512         // 8 waves -> 2 waves/SIMD -> 256-VGPR budget
#define NBLK 256        // grid (1 block/CU)
#define REDS 17         // padded red row stride (dwords)

typedef __attribute__((ext_vector_type(8))) short bf16x8;   // 8 bf16 (4 VGPRs)
typedef __attribute__((ext_vector_type(4))) float f32x4;    // MFMA C/D

// ---------- bf16 round-to-nearest-even ----------
__device__ __forceinline__ uint32_t bf16rne(float f) {
  uint32_t u = __float_as_uint(f);
  return (u + 0x7FFFu + ((u >> 16) & 1u)) >> 16;
}

// ---------- pack B fp32 -> two row-major bf16 planes (32 MB each) ----------
__global__ void pack_planes(const float* __restrict__ Br, const float* __restrict__ Bi,
                            uint4* __restrict__ Brb, uint4* __restrict__ Bib) {
  int i = blockIdx.x * blockDim.x + threadIdx.x;     // over N*N/8
  const float4* r4 = reinterpret_cast<const float4*>(Br) + (size_t)i * 2;
  const float4* m4 = reinterpret_cast<const float4*>(Bi) + (size_t)i * 2;
  float4 a0 = r4[0], a1 = r4[1];
  float4 b0 = m4[0], b1 = m4[1];
  uint4 o;
  o.x = bf16rne(a0.x) | (bf16rne(a0.y) << 16);
  o.y = bf16rne(a0.z) | (bf16rne(a0.w) << 16);
  o.z = bf16rne(a1.x) | (bf16rne(a1.y) << 16);
  o.w = bf16rne(a1.z) | (bf16rne(a1.w) << 16);
  Brb[i] = o;
  o.x = bf16rne(b0.x) | (bf16rne(b0.y) << 16);
  o.y = bf16rne(b0.z) | (bf16rne(b0.w) << 16);
  o.z = bf16rne(b1.x) | (bf16rne(b1.y) << 16);
  o.w = bf16rne(b1.z) | (bf16rne(b1.w) << 16);
  Bib[i] = o;
}

// ---------- flat grid barrier (round-12, proven): release/acquire on cnt[idx] ----------
__device__ __forceinline__ void gbar(uint32_t* cnt, int idx) {
  __syncthreads();                     // drain block's stores + block barrier
  if (threadIdx.x == 0) {
    __hip_atomic_fetch_add(&cnt[idx], 1u, __ATOMIC_RELEASE, __HIP_MEMORY_SCOPE_AGENT);
    while (__hip_atomic_load(&cnt[idx], __ATOMIC_RELAXED, __HIP_MEMORY_SCOPE_AGENT) < NBLK) {
      __builtin_amdgcn_s_sleep(1);
    }
    (void)__hip_atomic_load(&cnt[idx], __ATOMIC_ACQUIRE, __HIP_MEMORY_SCOPE_AGENT);
  }
  __syncthreads();
}

// ============================================================================
// Persistent kernel, 8 waves/block (2 waves/SIMD -> 256-VGPR budget).
// Each wave owns a 512-wide k-window: 32 bf16x8 B-fragments = 128 VGPRs,
// comfortably resident. In-loop asm pins force liveness across iterations.
// x state: flat bf16 planes xbuf[buf][plane c=2b+ri][node n], double-buffered.
// Fragment maps identical to rounds 10-13 (verified, absmax 0.0039).
// ============================================================================
__global__ __launch_bounds__(TPB, 2)
void rnn_persistent(const uint16_t* __restrict__ Brb,
                    const uint16_t* __restrict__ Bib,
                    const float* __restrict__ omega,
                    const float* __restrict__ ang,
                    uint16_t* __restrict__ xbuf,   // 2 * 8*NN bf16
                    uint32_t* __restrict__ cnt,    // NT barrier slots (zeroed)
                    float* __restrict__ out,
                    int NT) {
  __shared__ float red[8 * 16 * REDS];             // 8704 B

  const int tid  = threadIdx.x;
  const int w    = tid >> 6;       // 0..7, k-window of 512 nodes
  const int lane = tid & 63;
  const int al   = lane & 15;
  const int kq   = lane >> 4;
  const int row0 = blockIdx.x * MROWS;
  const int p1   = al & 7;
  const int p2   = p1 ^ 1;
  const uint64_t sm64 = (al & 1) ? 0ull : 0x8000800080008000ull;  // negate -xi (even cols)

  // ---- load 32 B fragments into registers (once; 128 VGPRs, resident) ----
  const uint16_t* arow = Brb + (size_t)(row0 + al) * NN + w * 512 + kq * 8;
  const uint16_t* brow = Bib + (size_t)(row0 + al) * NN + w * 512 + kq * 8;
  bf16x8 R0  = *(const bf16x8*)(arow +   0), I0  = *(const bf16x8*)(brow +   0);
  bf16x8 R1  = *(const bf16x8*)(arow +  32), I1  = *(const bf16x8*)(brow +  32);
  bf16x8 R2  = *(const bf16x8*)(arow +  64), I2  = *(const bf16x8*)(brow +  64);
  bf16x8 R3  = *(const bf16x8*)(arow +  96), I3  = *(const bf16x8*)(brow +  96);
  bf16x8 R4  = *(const bf16x8*)(arow + 128), I4  = *(const bf16x8*)(brow + 128);
  bf16x8 R5  = *(const bf16x8*)(arow + 160), I5  = *(const bf16x8*)(brow + 160);
  bf16x8 R6  = *(const bf16x8*)(arow + 192), I6  = *(const bf16x8*)(brow + 192);
  bf16x8 R7  = *(const bf16x8*)(arow + 224), I7  = *(const bf16x8*)(brow + 224);
  bf16x8 R8  = *(const bf16x8*)(arow + 256), I8  = *(const bf16x8*)(brow + 256);
  bf16x8 R9  = *(const bf16x8*)(arow + 288), I9  = *(const bf16x8*)(brow + 288);
  bf16x8 R10 = *(const bf16x8*)(arow + 320), I10 = *(const bf16x8*)(brow + 320);
  bf16x8 R11 = *(const bf16x8*)(arow + 352), I11 = *(const bf16x8*)(brow + 352);
  bf16x8 R12 = *(const bf16x8*)(arow + 384), I12 = *(const bf16x8*)(brow + 384);
  bf16x8 R13 = *(const bf16x8*)(arow + 416), I13 = *(const bf16x8*)(brow + 416);
  bf16x8 R14 = *(const bf16x8*)(arow + 448), I14 = *(const bf16x8*)(brow + 448);
  bf16x8 R15 = *(const bf16x8*)(arow + 480), I15 = *(const bf16x8*)(brow + 480);

  // ---- t=0: x0 = exp(i*theta); diag regs; out[0]; xbuf buffer 0 ----
  float myval = 0.f, om = 0.f;
  int bb = 0, mm = 0, ri = 0, cc = 0;
  if (tid < 128) {
    int r = tid >> 3; cc = tid & 7;
    mm = row0 + r; bb = cc >> 1; ri = cc & 1;
    om = omega[bb * NN + mm];
    float sv, cv;
    sincosf(ang[bb * NN + mm], &sv, &cv);
    myval = ri ? sv : cv;
    if (!ri) out[bb * NN + mm] = myval;
    xbuf[cc * NN + mm] = (uint16_t)bf16rne(myval);
  }
  gbar(cnt, 0);

  const int nb = w * 512 + kq * 8;                 // this lane's k-window base

  for (int t = 1; t < NT; ++t) {
    // pin fragments live-through every iteration (cannot be remat'd or dropped)
    asm volatile("" : "+v"(R0), "+v"(R1), "+v"(R2), "+v"(R3),
                      "+v"(R4), "+v"(R5), "+v"(R6), "+v"(R7));
    asm volatile("" : "+v"(R8), "+v"(R9), "+v"(R10), "+v"(R11),
                      "+v"(R12), "+v"(R13), "+v"(R14), "+v"(R15));
    asm volatile("" : "+v"(I0), "+v"(I1), "+v"(I2), "+v"(I3),
                      "+v"(I4), "+v"(I5), "+v"(I6), "+v"(I7));
    asm volatile("" : "+v"(I8), "+v"(I9), "+v"(I10), "+v"(I11),
                      "+v"(I12), "+v"(I13), "+v"(I14), "+v"(I15));

    const uint16_t* xs = xbuf + (size_t)((t - 1) & 1) * (8 * NN);
    f32x4 accA = {0.f, 0.f, 0.f, 0.f};
    f32x4 accB = {0.f, 0.f, 0.f, 0.f};

#define SSTEP(S, FR, FI)                                                        \
    { const uint16_t* x1p = xs + p1 * NN + nb + S * 32;                         \
      const uint16_t* x2p = xs + p2 * NN + nb + S * 32;                         \
      union { uint64_t q[2]; bf16x8 v; } u1, u2;                                \
      u1.q[0] = *(const uint64_t*)(x1p);                                        \
      u1.q[1] = *(const uint64_t*)(x1p + 4);                                    \
      u2.q[0] = *(const uint64_t*)(x2p) ^ sm64;                                 \
      u2.q[1] = *(const uint64_t*)(x2p + 4) ^ sm64;                             \
      accA = __builtin_amdgcn_mfma_f32_16x16x32_bf16(FR, u1.v, accA, 0, 0, 0);  \
      accB = __builtin_amdgcn_mfma_f32_16x16x32_bf16(FI, u2.v, accB, 0, 0, 0); }
    SSTEP(0,  R0,  I0)  SSTEP(1,  R1,  I1)  SSTEP(2,  R2,  I2)  SSTEP(3,  R3,  I3)
    SSTEP(4,  R4,  I4)  SSTEP(5,  R5,  I5)  SSTEP(6,  R6,  I6)  SSTEP(7,  R7,  I7)
    SSTEP(8,  R8,  I8)  SSTEP(9,  R9,  I9)  SSTEP(10, R10, I10) SSTEP(11, R11, I11)
    SSTEP(12, R12, I12) SSTEP(13, R13, I13) SSTEP(14, R14, I14) SSTEP(15, R15, I15)
#undef SSTEP

    // ---- partial tiles -> padded LDS ----
    {
      float* rw = red + w * 16 * REDS;
      rw[(kq * 4 + 0) * REDS + al] = accA[0] + accB[0];
      rw[(kq * 4 + 1) * REDS + al] = accA[1] + accB[1];
      rw[(kq * 4 + 2) * REDS + al] = accA[2] + accB[2];
      rw[(kq * 4 + 3) * REDS + al] = accA[3] + accB[3];
    }
    __syncthreads();

    // ---- cross-wave sum + diagonal + writes ----
    if (tid < 128) {
      int r = tid >> 3;
      float s = 0.f;
#pragma unroll
      for (int w2 = 0; w2 < 8; ++w2) s += red[w2 * 16 * REDS + r * REDS + cc];
      float other = __shfl_xor(myval, 1, 64);
      float xr = ri ? other : myval;
      float xi = ri ? myval : other;
      // i*omega*(xr + i*xi) = -omega*xi + i*omega*xr
      s += ri ? (om * xr) : (-om * xi);
      myval = s;                                   // fp32 diag chain stays in reg
      if (!ri) out[(size_t)t * (BB * NN) + bb * NN + mm] = s;
      xbuf[(size_t)(t & 1) * (8 * NN) + cc * NN + mm] = (uint16_t)bf16rne(s);
    }

    if (t < NT - 1) gbar(cnt, t);
  }
}

// ============================================================================
// Fallback (fp32 B direct, per-step launches) — only if coop launch fails.
// ============================================================================
__global__ void init_kernel(const float* __restrict__ ang,
                            float2* __restrict__ st0, float* __restrict__ out0) {
  int i = blockIdx.x * blockDim.x + threadIdx.x;
  if (i < BB * NN) {
    float s, c;
    sincosf(ang[i], &s, &c);
    st0[i] = make_float2(c, s);
    out0[i] = c;
  }
}

__global__ __launch_bounds__(1024)
void step_fb(const float* __restrict__ Brf, const float* __restrict__ Bif,
             const float* __restrict__ omega,
             const float2* __restrict__ stPrev, float2* __restrict__ stNext,
             float* __restrict__ outRe) {
  extern __shared__ float lds[];
  float* xl  = lds;
  float* xh  = lds + NN * 4;
  float* red = lds + NN * 8;
  const int tid = threadIdx.x;
#pragma unroll
  for (int k = 0; k < 8; ++k) {
    int idx = tid + k * 1024;
    int half = idx >> 12;
    int n = idx & (NN - 1);
    float2 v0 = stPrev[(half * 2) * NN + n];
    float2 v1 = stPrev[(half * 2 + 1) * NN + n];
    reinterpret_cast<float4*>(half ? xh : xl)[n] = make_float4(v0.x, v0.y, v1.x, v1.y);
  }
  __syncthreads();
  const int w = tid >> 6, lane = tid & 63, rg = w >> 2, q = w & 3;
  const int row0 = blockIdx.x * MROWS + rg * 4;
  float acc[4][8];
#pragma unroll
  for (int r = 0; r < 4; ++r)
#pragma unroll
    for (int c = 0; c < 8; ++c) acc[r][c] = 0.0f;
#define CFMA(A, BR, BI, XA, XB)                                   \
  A[0] = fmaf(BR, XA.x, A[0]); A[0] = fmaf(-BI, XA.y, A[0]);      \
  A[1] = fmaf(BR, XA.y, A[1]); A[1] = fmaf(BI, XA.x, A[1]);       \
  A[2] = fmaf(BR, XA.z, A[2]); A[2] = fmaf(-BI, XA.w, A[2]);      \
  A[3] = fmaf(BR, XA.w, A[3]); A[3] = fmaf(BI, XA.z, A[3]);       \
  A[4] = fmaf(BR, XB.x, A[4]); A[4] = fmaf(-BI, XB.y, A[4]);      \
  A[5] = fmaf(BR, XB.y, A[5]); A[5] = fmaf(BI, XB.x, A[5]);       \
  A[6] = fmaf(BR, XB.z, A[6]); A[6] = fmaf(-BI, XB.w, A[6]);      \
  A[7] = fmaf(BR, XB.w, A[7]); A[7] = fmaf(BI, XB.z, A[7]);
  for (int i4 = 0; i4 < 4; ++i4) {
    const int n0 = q * 1024 + i4 * 256 + lane * 4;
    float4 xa[4], xb[4];
#pragma unroll
    for (int j = 0; j < 4; ++j) {
      xa[j] = reinterpret_cast<const float4*>(xl)[n0 + j];
      xb[j] = reinterpret_cast<const float4*>(xh)[n0 + j];
    }
#pragma unroll
    for (int r = 0; r < 4; ++r) {
      const float4 pvr = reinterpret_cast<const float4*>(Brf + (size_t)(row0 + r) * NN)[q * 256 + i4 * 64 + lane];
      const float4 pvi = reinterpret_cast<const float4*>(Bif + (size_t)(row0 + r) * NN)[q * 256 + i4 * 64 + lane];
      float* a = acc[r];
      CFMA(a, pvr.x, pvi.x, xa[0], xb[0]);
      CFMA(a, pvr.y, pvi.y, xa[1], xb[1]);
      CFMA(a, pvr.z, pvi.z, xa[2], xb[2]);
      CFMA(a, pvr.w, pvi.w, xa[3], xb[3]);
    }
  }
#undef CFMA
  float t0 = acc[0][0], t1 = acc[0][1], t2 = acc[0][2], t3 = acc[0][3];
  float t4 = acc[0][4], t5 = acc[0][5], t6 = acc[0][6], t7 = acc[0][7];
  float t8 = acc[1][0], t9 = acc[1][1], t10 = acc[1][2], t11 = acc[1][3];
  float t12 = acc[1][4], t13 = acc[1][5], t14 = acc[1][6], t15 = acc[1][7];
  float t16 = acc[2][0], t17 = acc[2][1], t18 = acc[2][2], t19 = acc[2][3];
  float t20 = acc[2][4], t21 = acc[2][5], t22 = acc[2][6], t23 = acc[2][7];
  float t24 = acc[3][0], t25 = acc[3][1], t26 = acc[3][2], t27 = acc[3][3];
  float t28 = acc[3][4], t29 = acc[3][5], t30 = acc[3][6], t31 = acc[3][7];
#define RSTEP(LO, HI, M)                                          \
  { float s_ = up ? LO : HI;                                      \
    s_ = __shfl_xor(s_, M, 64);                                   \
    LO = (up ? HI : LO) + s_; }
  { const bool up = (lane & 32) != 0;
    RSTEP(t0, t16, 32)  RSTEP(t1, t17, 32)  RSTEP(t2, t18, 32)  RSTEP(t3, t19, 32)
    RSTEP(t4, t20, 32)  RSTEP(t5, t21, 32)  RSTEP(t6, t22, 32)  RSTEP(t7, t23, 32)
    RSTEP(t8, t24, 32)  RSTEP(t9, t25, 32)  RSTEP(t10, t26, 32) RSTEP(t11, t27, 32)
    RSTEP(t12, t28, 32) RSTEP(t13, t29, 32) RSTEP(t14, t30, 32) RSTEP(t15, t31, 32) }
  { const bool up = (lane & 16) != 0;
    RSTEP(t0, t8, 16)  RSTEP(t1, t9, 16)  RSTEP(t2, t10, 16) RSTEP(t3, t11, 16)
    RSTEP(t4, t12, 16) RSTEP(t5, t13, 16) RSTEP(t6, t14, 16) RSTEP(t7, t15, 16) }
  { const bool up = (lane & 8) != 0;
    RSTEP(t0, t4, 8) RSTEP(t1, t5, 8) RSTEP(t2, t6, 8) RSTEP(t3, t7, 8) }
  { const bool up = (lane & 4) != 0;
    RSTEP(t0, t2, 4) RSTEP(t1, t3, 4) }
  { const bool up = (lane & 2) != 0;
    RSTEP(t0, t1, 2) }
#undef RSTEP
  t0 += __shfl_xor(t0, 1, 64);
  if (!(lane & 1)) red[w * 32 + ((lane >> 1) & 31)] = t0;
  __syncthreads();
  if (tid < 128) {
    int rg2 = tid >> 5, v = tid & 31;
    float s = red[(rg2 * 4 + 0) * 32 + v] + red[(rg2 * 4 + 1) * 32 + v] +
              red[(rg2 * 4 + 2) * 32 + v] + red[(rg2 * 4 + 3) * 32 + v];
    int r = v >> 3, c = v & 7, b = c >> 1, ri = c & 1;
    int m = blockIdx.x * MROWS + rg2 * 4 + r;
    float om = omega[b * NN + m];
    const float* xs = (b < 2) ? xl : xh;
    float xr = xs[m * 4 + (b & 1) * 2];
    float xi = xs[m * 4 + (b & 1) * 2 + 1];
    s += (ri == 0) ? (-om * xi) : (om * xr);
    reinterpret_cast<float*>(stNext)[(b * NN + m) * 2 + ri] = s;
    if (ri == 0) outRe[b * NN + m] = s;
  }
}

// ---------- host ----------
extern "C" void kernel_launch(void* const* d_in, const int* in_sizes, int n_in,
                              void* d_out, int out_size, void* d_ws, size_t ws_size,
                              hipStream_t stream) {
  const float* B_real = (const float*)d_in[0];
  const float* B_imag = (const float*)d_in[1];
  const float* omega  = (const float*)d_in[2];
  const float* ang    = (const float*)d_in[3];
  float* out = (float*)d_out;

  int NT = out_size / (BB * NN);                                 // 256
  const size_t planeBytes = (size_t)NN * NN * 2;                 // 32 MB
  const size_t xbufBytes  = (size_t)2 * 8 * NN * 2;              // 128 KB
  const size_t cntBytes   = 1024;                                // NT barrier slots
  const bool coop = ws_size >= 2 * planeBytes + xbufBytes + cntBytes;

  hipError_t launched = hipErrorUnknown;
  if (coop) {
    uint16_t* Brb = (uint16_t*)d_ws;
    uint16_t* Bib = Brb + (size_t)NN * NN;
    uint16_t* xbuf = (uint16_t*)((char*)d_ws + 2 * planeBytes);
    uint32_t* cnt  = (uint32_t*)((char*)d_ws + 2 * planeBytes + xbufBytes);

    (void)hipMemsetAsync((void*)cnt, 0, cntBytes, stream);       // counters -> 0
    pack_planes<<<NN * NN / 8 / 256, 256, 0, stream>>>(B_real, B_imag,
                                                       (uint4*)Brb, (uint4*)Bib);

    void* kargs[8];
    kargs[0] = (void*)&Brb;
    kargs[1] = (void*)&Bib;
    kargs[2] = (void*)&omega;
    kargs[3] = (void*)&ang;
    kargs[4] = (void*)&xbuf;
    kargs[5] = (void*)&cnt;
    kargs[6] = (void*)&out;
    kargs[7] = (void*)&NT;
    launched = hipLaunchCooperativeKernel((const void*)&rnn_persistent,
                                          dim3(NBLK), dim3(TPB),
                                          kargs, 0, stream);
  }

  if (launched != hipSuccess) {
    // fallback: per-step launches, fp32 B from inputs, state ping-pong in ws
    float2* st0 = (float2*)d_ws;
    float2* st1 = st0 + BB * NN;
    const size_t shmemF = (size_t)(NN * 8 + 16 * 32) * sizeof(float);
    (void)hipFuncSetAttribute((const void*)&step_fb,
                              hipFuncAttributeMaxDynamicSharedMemorySize, (int)shmemF);
    init_kernel<<<(BB * NN + 255) / 256, 256, 0, stream>>>(ang, st0, out);
    for (int t = 1; t < NT; ++t) {
      float2* sp = ((t - 1) & 1) ? st1 : st0;
      float2* sn = (t & 1) ? st1 : st0;
      float* outT = out + (size_t)t * BB * NN;
      step_fb<<<NN / MROWS, 1024, shmemF, stream>>>(B_real, B_imag, omega, sp, sn, outT);
    }
  }
}

// Round 15
// 4252.121 us; speedup vs baseline: 1.1116x; 1.0438x over previous
//
#include <hip/hip_runtime.h>
#include <stdint.h>

#define NN 4096
#define BB 4
#define MROWS 16        // rows per block
#define TPB 512         // 8 waves -> 2 waves/SIMD -> 256-reg unified budget
#define NBLK 256        // grid (1 block/CU)
#define REDS 17         // padded red row stride (dwords)

typedef __attribute__((ext_vector_type(8))) short bf16x8;   // 8 bf16 (4 regs)
typedef __attribute__((ext_vector_type(4))) float f32x4;    // MFMA C/D

// ---------- bf16 round-to-nearest-even ----------
__device__ __forceinline__ uint32_t bf16rne(float f) {
  uint32_t u = __float_as_uint(f);
  return (u + 0x7FFFu + ((u >> 16) & 1u)) >> 16;
}

// ---------- pack B fp32 -> two row-major bf16 planes (32 MB each) ----------
__global__ void pack_planes(const float* __restrict__ Br, const float* __restrict__ Bi,
                            uint4* __restrict__ Brb, uint4* __restrict__ Bib) {
  int i = blockIdx.x * blockDim.x + threadIdx.x;     // over N*N/8
  const float4* r4 = reinterpret_cast<const float4*>(Br) + (size_t)i * 2;
  const float4* m4 = reinterpret_cast<const float4*>(Bi) + (size_t)i * 2;
  float4 a0 = r4[0], a1 = r4[1];
  float4 b0 = m4[0], b1 = m4[1];
  uint4 o;
  o.x = bf16rne(a0.x) | (bf16rne(a0.y) << 16);
  o.y = bf16rne(a0.z) | (bf16rne(a0.w) << 16);
  o.z = bf16rne(a1.x) | (bf16rne(a1.y) << 16);
  o.w = bf16rne(a1.z) | (bf16rne(a1.w) << 16);
  Brb[i] = o;
  o.x = bf16rne(b0.x) | (bf16rne(b0.y) << 16);
  o.y = bf16rne(b0.z) | (bf16rne(b0.w) << 16);
  o.z = bf16rne(b1.x) | (bf16rne(b1.y) << 16);
  o.w = bf16rne(b1.z) | (bf16rne(b1.w) << 16);
  Bib[i] = o;
}

// ---------- flat grid barrier (round-12, proven): release/acquire on cnt[idx] ----------
__device__ __forceinline__ void gbar(uint32_t* cnt, int idx) {
  __syncthreads();                     // drain block's stores + block barrier
  if (threadIdx.x == 0) {
    __hip_atomic_fetch_add(&cnt[idx], 1u, __ATOMIC_RELEASE, __HIP_MEMORY_SCOPE_AGENT);
    while (__hip_atomic_load(&cnt[idx], __ATOMIC_RELAXED, __HIP_MEMORY_SCOPE_AGENT) < NBLK) {
      __builtin_amdgcn_s_sleep(1);
    }
    (void)__hip_atomic_load(&cnt[idx], __ATOMIC_ACQUIRE, __HIP_MEMORY_SCOPE_AGENT);
  }
  __syncthreads();
}

// ============================================================================
// Persistent kernel, 8 waves/block (2 waves/SIMD -> 256-reg unified budget).
// Each wave owns a 512-wide k-window: 32 bf16x8 B-fragments = 128 AGPRs,
// pinned into the AGPR class via "+a" asm (gfx950 MFMA reads A/B from AGPR
// directly; AGPR values cannot be rematerialized from memory).
// x state: flat bf16 planes xbuf[buf][plane c=2b+ri][node n], double-buffered.
// Fragment maps identical to rounds 10-14 (verified, absmax 0.0039).
// ============================================================================
__global__ __launch_bounds__(TPB, 2)
void rnn_persistent(const uint16_t* __restrict__ Brb,
                    const uint16_t* __restrict__ Bib,
                    const float* __restrict__ omega,
                    const float* __restrict__ ang,
                    uint16_t* __restrict__ xbuf,   // 2 * 8*NN bf16
                    uint32_t* __restrict__ cnt,    // NT barrier slots (zeroed)
                    float* __restrict__ out,
                    int NT) {
  __shared__ float red[8 * 16 * REDS];             // 8704 B

  const int tid  = threadIdx.x;
  const int w    = tid >> 6;       // 0..7, k-window of 512 nodes
  const int lane = tid & 63;
  const int al   = lane & 15;
  const int kq   = lane >> 4;
  const int row0 = blockIdx.x * MROWS;
  const int p1   = al & 7;
  const int p2   = p1 ^ 1;
  const uint64_t sm64 = (al & 1) ? 0ull : 0x8000800080008000ull;  // negate -xi (even cols)

  // ---- load 32 B fragments (once) ----
  const uint16_t* arow = Brb + (size_t)(row0 + al) * NN + w * 512 + kq * 8;
  const uint16_t* brow = Bib + (size_t)(row0 + al) * NN + w * 512 + kq * 8;
  bf16x8 R0  = *(const bf16x8*)(arow +   0), I0  = *(const bf16x8*)(brow +   0);
  bf16x8 R1  = *(const bf16x8*)(arow +  32), I1  = *(const bf16x8*)(brow +  32);
  bf16x8 R2  = *(const bf16x8*)(arow +  64), I2  = *(const bf16x8*)(brow +  64);
  bf16x8 R3  = *(const bf16x8*)(arow +  96), I3  = *(const bf16x8*)(brow +  96);
  bf16x8 R4  = *(const bf16x8*)(arow + 128), I4  = *(const bf16x8*)(brow + 128);
  bf16x8 R5  = *(const bf16x8*)(arow + 160), I5  = *(const bf16x8*)(brow + 160);
  bf16x8 R6  = *(const bf16x8*)(arow + 192), I6  = *(const bf16x8*)(brow + 192);
  bf16x8 R7  = *(const bf16x8*)(arow + 224), I7  = *(const bf16x8*)(brow + 224);
  bf16x8 R8  = *(const bf16x8*)(arow + 256), I8  = *(const bf16x8*)(brow + 256);
  bf16x8 R9  = *(const bf16x8*)(arow + 288), I9  = *(const bf16x8*)(brow + 288);
  bf16x8 R10 = *(const bf16x8*)(arow + 320), I10 = *(const bf16x8*)(brow + 320);
  bf16x8 R11 = *(const bf16x8*)(arow + 352), I11 = *(const bf16x8*)(brow + 352);
  bf16x8 R12 = *(const bf16x8*)(arow + 384), I12 = *(const bf16x8*)(brow + 384);
  bf16x8 R13 = *(const bf16x8*)(arow + 416), I13 = *(const bf16x8*)(brow + 416);
  bf16x8 R14 = *(const bf16x8*)(arow + 448), I14 = *(const bf16x8*)(brow + 448);
  bf16x8 R15 = *(const bf16x8*)(arow + 480), I15 = *(const bf16x8*)(brow + 480);

  // ---- establish AGPR residency (cannot be remat'd from memory) ----
  asm volatile("" : "+a"(R0), "+a"(R1), "+a"(R2), "+a"(R3),
                    "+a"(R4), "+a"(R5), "+a"(R6), "+a"(R7));
  asm volatile("" : "+a"(R8), "+a"(R9), "+a"(R10), "+a"(R11),
                    "+a"(R12), "+a"(R13), "+a"(R14), "+a"(R15));
  asm volatile("" : "+a"(I0), "+a"(I1), "+a"(I2), "+a"(I3),
                    "+a"(I4), "+a"(I5), "+a"(I6), "+a"(I7));
  asm volatile("" : "+a"(I8), "+a"(I9), "+a"(I10), "+a"(I11),
                    "+a"(I12), "+a"(I13), "+a"(I14), "+a"(I15));

  // ---- t=0: x0 = exp(i*theta); diag regs; out[0]; xbuf buffer 0 ----
  float myval = 0.f, om = 0.f;
  int bb = 0, mm = 0, ri = 0, cc = 0;
  if (tid < 128) {
    int r = tid >> 3; cc = tid & 7;
    mm = row0 + r; bb = cc >> 1; ri = cc & 1;
    om = omega[bb * NN + mm];
    float sv, cv;
    sincosf(ang[bb * NN + mm], &sv, &cv);
    myval = ri ? sv : cv;
    if (!ri) out[bb * NN + mm] = myval;
    xbuf[cc * NN + mm] = (uint16_t)bf16rne(myval);
  }
  gbar(cnt, 0);

  const int nb = w * 512 + kq * 8;                 // this lane's k-window base

  for (int t = 1; t < NT; ++t) {
    // anchor fragments in AGPR class each iteration (keeps them live, class a)
    asm volatile("" : "+a"(R0), "+a"(R1), "+a"(R2), "+a"(R3),
                      "+a"(R4), "+a"(R5), "+a"(R6), "+a"(R7));
    asm volatile("" : "+a"(R8), "+a"(R9), "+a"(R10), "+a"(R11),
                      "+a"(R12), "+a"(R13), "+a"(R14), "+a"(R15));
    asm volatile("" : "+a"(I0), "+a"(I1), "+a"(I2), "+a"(I3),
                      "+a"(I4), "+a"(I5), "+a"(I6), "+a"(I7));
    asm volatile("" : "+a"(I8), "+a"(I9), "+a"(I10), "+a"(I11),
                      "+a"(I12), "+a"(I13), "+a"(I14), "+a"(I15));

    const uint16_t* xs = xbuf + (size_t)((t - 1) & 1) * (8 * NN);
    f32x4 accA = {0.f, 0.f, 0.f, 0.f};
    f32x4 accB = {0.f, 0.f, 0.f, 0.f};

#define SSTEP(S, FR, FI)                                                        \
    { const uint16_t* x1p = xs + p1 * NN + nb + S * 32;                         \
      const uint16_t* x2p = xs + p2 * NN + nb + S * 32;                         \
      union { uint64_t q[2]; bf16x8 v; } u1, u2;                                \
      u1.q[0] = *(const uint64_t*)(x1p);                                        \
      u1.q[1] = *(const uint64_t*)(x1p + 4);                                    \
      u2.q[0] = *(const uint64_t*)(x2p) ^ sm64;                                 \
      u2.q[1] = *(const uint64_t*)(x2p + 4) ^ sm64;                             \
      accA = __builtin_amdgcn_mfma_f32_16x16x32_bf16(FR, u1.v, accA, 0, 0, 0);  \
      accB = __builtin_amdgcn_mfma_f32_16x16x32_bf16(FI, u2.v, accB, 0, 0, 0); }
    SSTEP(0,  R0,  I0)  SSTEP(1,  R1,  I1)  SSTEP(2,  R2,  I2)  SSTEP(3,  R3,  I3)
    SSTEP(4,  R4,  I4)  SSTEP(5,  R5,  I5)  SSTEP(6,  R6,  I6)  SSTEP(7,  R7,  I7)
    SSTEP(8,  R8,  I8)  SSTEP(9,  R9,  I9)  SSTEP(10, R10, I10) SSTEP(11, R11, I11)
    SSTEP(12, R12, I12) SSTEP(13, R13, I13) SSTEP(14, R14, I14) SSTEP(15, R15, I15)
#undef SSTEP

    // ---- partial tiles -> padded LDS ----
    {
      float* rw = red + w * 16 * REDS;
      rw[(kq * 4 + 0) * REDS + al] = accA[0] + accB[0];
      rw[(kq * 4 + 1) * REDS + al] = accA[1] + accB[1];
      rw[(kq * 4 + 2) * REDS + al] = accA[2] + accB[2];
      rw[(kq * 4 + 3) * REDS + al] = accA[3] + accB[3];
    }
    __syncthreads();

    // ---- cross-wave sum + diagonal + writes ----
    if (tid < 128) {
      int r = tid >> 3;
      float s = 0.f;
#pragma unroll
      for (int w2 = 0; w2 < 8; ++w2) s += red[w2 * 16 * REDS + r * REDS + cc];
      float other = __shfl_xor(myval, 1, 64);
      float xr = ri ? other : myval;
      float xi = ri ? myval : other;
      // i*omega*(xr + i*xi) = -omega*xi + i*omega*xr
      s += ri ? (om * xr) : (-om * xi);
      myval = s;                                   // fp32 diag chain stays in reg
      if (!ri) out[(size_t)t * (BB * NN) + bb * NN + mm] = s;
      xbuf[(size_t)(t & 1) * (8 * NN) + cc * NN + mm] = (uint16_t)bf16rne(s);
    }

    if (t < NT - 1) gbar(cnt, t);
  }
}

// ============================================================================
// Fallback (fp32 B direct, per-step launches) — only if coop launch fails.
// ============================================================================
__global__ void init_kernel(const float* __restrict__ ang,
                            float2* __restrict__ st0, float* __restrict__ out0) {
  int i = blockIdx.x * blockDim.x + threadIdx.x;
  if (i < BB * NN) {
    float s, c;
    sincosf(ang[i], &s, &c);
    st0[i] = make_float2(c, s);
    out0[i] = c;
  }
}

__global__ __launch_bounds__(1024)
void step_fb(const float* __restrict__ Brf, const float* __restrict__ Bif,
             const float* __restrict__ omega,
             const float2* __restrict__ stPrev, float2* __restrict__ stNext,
             float* __restrict__ outRe) {
  extern __shared__ float lds[];
  float* xl  = lds;
  float* xh  = lds + NN * 4;
  float* red = lds + NN * 8;
  const int tid = threadIdx.x;
#pragma unroll
  for (int k = 0; k < 8; ++k) {
    int idx = tid + k * 1024;
    int half = idx >> 12;
    int n = idx & (NN - 1);
    float2 v0 = stPrev[(half * 2) * NN + n];
    float2 v1 = stPrev[(half * 2 + 1) * NN + n];
    reinterpret_cast<float4*>(half ? xh : xl)[n] = make_float4(v0.x, v0.y, v1.x, v1.y);
  }
  __syncthreads();
  const int w = tid >> 6, lane = tid & 63, rg = w >> 2, q = w & 3;
  const int row0 = blockIdx.x * MROWS + rg * 4;
  float acc[4][8];
#pragma unroll
  for (int r = 0; r < 4; ++r)
#pragma unroll
    for (int c = 0; c < 8; ++c) acc[r][c] = 0.0f;
#define CFMA(A, BR, BI, XA, XB)                                   \
  A[0] = fmaf(BR, XA.x, A[0]); A[0] = fmaf(-BI, XA.y, A[0]);      \
  A[1] = fmaf(BR, XA.y, A[1]); A[1] = fmaf(BI, XA.x, A[1]);       \
  A[2] = fmaf(BR, XA.z, A[2]); A[2] = fmaf(-BI, XA.w, A[2]);      \
  A[3] = fmaf(BR, XA.w, A[3]); A[3] = fmaf(BI, XA.z, A[3]);       \
  A[4] = fmaf(BR, XB.x, A[4]); A[4] = fmaf(-BI, XB.y, A[4]);      \
  A[5] = fmaf(BR, XB.y, A[5]); A[5] = fmaf(BI, XB.x, A[5]);       \
  A[6] = fmaf(BR, XB.z, A[6]); A[6] = fmaf(-BI, XB.w, A[6]);      \
  A[7] = fmaf(BR, XB.w, A[7]); A[7] = fmaf(BI, XB.z, A[7]);
  for (int i4 = 0; i4 < 4; ++i4) {
    const int n0 = q * 1024 + i4 * 256 + lane * 4;
    float4 xa[4], xb[4];
#pragma unroll
    for (int j = 0; j < 4; ++j) {
      xa[j] = reinterpret_cast<const float4*>(xl)[n0 + j];
      xb[j] = reinterpret_cast<const float4*>(xh)[n0 + j];
    }
#pragma unroll
    for (int r = 0; r < 4; ++r) {
      const float4 pvr = reinterpret_cast<const float4*>(Brf + (size_t)(row0 + r) * NN)[q * 256 + i4 * 64 + lane];
      const float4 pvi = reinterpret_cast<const float4*>(Bif + (size_t)(row0 + r) * NN)[q * 256 + i4 * 64 + lane];
      float* a = acc[r];
      CFMA(a, pvr.x, pvi.x, xa[0], xb[0]);
      CFMA(a, pvr.y, pvi.y, xa[1], xb[1]);
      CFMA(a, pvr.z, pvi.z, xa[2], xb[2]);
      CFMA(a, pvr.w, pvi.w, xa[3], xb[3]);
    }
  }
#undef CFMA
  float t0 = acc[0][0], t1 = acc[0][1], t2 = acc[0][2], t3 = acc[0][3];
  float t4 = acc[0][4], t5 = acc[0][5], t6 = acc[0][6], t7 = acc[0][7];
  float t8 = acc[1][0], t9 = acc[1][1], t10 = acc[1][2], t11 = acc[1][3];
  float t12 = acc[1][4], t13 = acc[1][5], t14 = acc[1][6], t15 = acc[1][7];
  float t16 = acc[2][0], t17 = acc[2][1], t18 = acc[2][2], t19 = acc[2][3];
  float t20 = acc[2][4], t21 = acc[2][5], t22 = acc[2][6], t23 = acc[2][7];
  float t24 = acc[3][0], t25 = acc[3][1], t26 = acc[3][2], t27 = acc[3][3];
  float t28 = acc[3][4], t29 = acc[3][5], t30 = acc[3][6], t31 = acc[3][7];
#define RSTEP(LO, HI, M)                                          \
  { float s_ = up ? LO : HI;                                      \
    s_ = __shfl_xor(s_, M, 64);                                   \
    LO = (up ? HI : LO) + s_; }
  { const bool up = (lane & 32) != 0;
    RSTEP(t0, t16, 32)  RSTEP(t1, t17, 32)  RSTEP(t2, t18, 32)  RSTEP(t3, t19, 32)
    RSTEP(t4, t20, 32)  RSTEP(t5, t21, 32)  RSTEP(t6, t22, 32)  RSTEP(t7, t23, 32)
    RSTEP(t8, t24, 32)  RSTEP(t9, t25, 32)  RSTEP(t10, t26, 32) RSTEP(t11, t27, 32)
    RSTEP(t12, t28, 32) RSTEP(t13, t29, 32) RSTEP(t14, t30, 32) RSTEP(t15, t31, 32) }
  { const bool up = (lane & 16) != 0;
    RSTEP(t0, t8, 16)  RSTEP(t1, t9, 16)  RSTEP(t2, t10, 16) RSTEP(t3, t11, 16)
    RSTEP(t4, t12, 16) RSTEP(t5, t13, 16) RSTEP(t6, t14, 16) RSTEP(t7, t15, 16) }
  { const bool up = (lane & 8) != 0;
    RSTEP(t0, t4, 8) RSTEP(t1, t5, 8) RSTEP(t2, t6, 8) RSTEP(t3, t7, 8) }
  { const bool up = (lane & 4) != 0;
    RSTEP(t0, t2, 4) RSTEP(t1, t3, 4) }
  { const bool up = (lane & 2) != 0;
    RSTEP(t0, t1, 2) }
#undef RSTEP
  t0 += __shfl_xor(t0, 1, 64);
  if (!(lane & 1)) red[w * 32 + ((lane >> 1) & 31)] = t0;
  __syncthreads();
  if (tid < 128) {
    int rg2 = tid >> 5, v = tid & 31;
    float s = red[(rg2 * 4 + 0) * 32 + v] + red[(rg2 * 4 + 1) * 32 + v] +
              red[(rg2 * 4 + 2) * 32 + v] + red[(rg2 * 4 + 3) * 32 + v];
    int r = v >> 3, c = v & 7, b = c >> 1, ri = c & 1;
    int m = blockIdx.x * MROWS + rg2 * 4 + r;
    float om = omega[b * NN + m];
    const float* xs = (b < 2) ? xl : xh;
    float xr = xs[m * 4 + (b & 1) * 2];
    float xi = xs[m * 4 + (b & 1) * 2 + 1];
    s += (ri == 0) ? (-om * xi) : (om * xr);
    reinterpret_cast<float*>(stNext)[(b * NN + m) * 2 + ri] = s;
    if (ri == 0) outRe[b * NN + m] = s;
  }
}

// ---------- host ----------
extern "C" void kernel_launch(void* const* d_in, const int* in_sizes, int n_in,
                              void* d_out, int out_size, void* d_ws, size_t ws_size,
                              hipStream_t stream) {
  const float* B_real = (const float*)d_in[0];
  const float* B_imag = (const float*)d_in[1];
  const float* omega  = (const float*)d_in[2];
  const float* ang    = (const float*)d_in[3];
  float* out = (float*)d_out;

  int NT = out_size / (BB * NN);                                 // 256
  const size_t planeBytes = (size_t)NN * NN * 2;                 // 32 MB
  const size_t xbufBytes  = (size_t)2 * 8 * NN * 2;              // 128 KB
  const size_t cntBytes   = 1024;                                // NT barrier slots
  const bool coop = ws_size >= 2 * planeBytes + xbufBytes + cntBytes;

  hipError_t launched = hipErrorUnknown;
  if (coop) {
    uint16_t* Brb = (uint16_t*)d_ws;
    uint16_t* Bib = Brb + (size_t)NN * NN;
    uint16_t* xbuf = (uint16_t*)((char*)d_ws + 2 * planeBytes);
    uint32_t* cnt  = (uint32_t*)((char*)d_ws + 2 * planeBytes + xbufBytes);

    (void)hipMemsetAsync((void*)cnt, 0, cntBytes, stream);       // counters -> 0
    pack_planes<<<NN * NN / 8 / 256, 256, 0, stream>>>(B_real, B_imag,
                                                       (uint4*)Brb, (uint4*)Bib);

    void* kargs[8];
    kargs[0] = (void*)&Brb;
    kargs[1] = (void*)&Bib;
    kargs[2] = (void*)&omega;
    kargs[3] = (void*)&ang;
    kargs[4] = (void*)&xbuf;
    kargs[5] = (void*)&cnt;
    kargs[6] = (void*)&out;
    kargs[7] = (void*)&NT;
    launched = hipLaunchCooperativeKernel((const void*)&rnn_persistent,
                                          dim3(NBLK), dim3(TPB),
                                          kargs, 0, stream);
  }

  if (launched != hipSuccess) {
    // fallback: per-step launches, fp32 B from inputs, state ping-pong in ws
    float2* st0 = (float2*)d_ws;
    float2* st1 = st0 + BB * NN;
    const size_t shmemF = (size_t)(NN * 8 + 16 * 32) * sizeof(float);
    (void)hipFuncSetAttribute((const void*)&step_fb,
                              hipFuncAttributeMaxDynamicSharedMemorySize, (int)shmemF);
    init_kernel<<<(BB * NN + 255) / 256, 256, 0, stream>>>(ang, st0, out);
    for (int t = 1; t < NT; ++t) {
      float2* sp = ((t - 1) & 1) ? st1 : st0;
      float2* sn = (t & 1) ? st1 : st0;
      float* outT = out + (size_t)t * BB * NN;
      step_fb<<<NN / MROWS, 1024, shmemF, stream>>>(B_real, B_imag, omega, sp, sn, outT);
    }
  }
}

// Round 16
// 2362.604 us; speedup vs baseline: 2.0007x; 1.7998x over previous
//
#include <hip/hip_runtime.h>
#include <stdint.h>

#define NN 4096
#define BB 4
#define MROWS 16        // rows per block
#define TPB 512         // 8 waves
#define NBLK 256        // grid (1 block/CU)
#define REDS 17         // padded red row stride (dwords)
#define RING 16         // x-state ring depth (first-touch freshness)
#define XSZ  (8 * NN)   // u16 elements per ring slot (8 planes x NN)

typedef __attribute__((ext_vector_type(8))) short bf16x8;   // 8 bf16 (4 regs)
typedef __attribute__((ext_vector_type(4))) float f32x4;    // MFMA C/D

// ---------- bf16 round-to-nearest-even ----------
__device__ __forceinline__ uint32_t bf16rne(float f) {
  uint32_t u = __float_as_uint(f);
  return (u + 0x7FFFu + ((u >> 16) & 1u)) >> 16;
}

// ---------- pack B fp32 -> two row-major bf16 planes (32 MB each) ----------
__global__ void pack_planes(const float* __restrict__ Br, const float* __restrict__ Bi,
                            uint4* __restrict__ Brb, uint4* __restrict__ Bib) {
  int i = blockIdx.x * blockDim.x + threadIdx.x;     // over N*N/8
  const float4* r4 = reinterpret_cast<const float4*>(Br) + (size_t)i * 2;
  const float4* m4 = reinterpret_cast<const float4*>(Bi) + (size_t)i * 2;
  float4 a0 = r4[0], a1 = r4[1];
  float4 b0 = m4[0], b1 = m4[1];
  uint4 o;
  o.x = bf16rne(a0.x) | (bf16rne(a0.y) << 16);
  o.y = bf16rne(a0.z) | (bf16rne(a0.w) << 16);
  o.z = bf16rne(a1.x) | (bf16rne(a1.y) << 16);
  o.w = bf16rne(a1.z) | (bf16rne(a1.w) << 16);
  Brb[i] = o;
  o.x = bf16rne(b0.x) | (bf16rne(b0.y) << 16);
  o.y = bf16rne(b0.z) | (bf16rne(b0.w) << 16);
  o.z = bf16rne(b1.x) | (bf16rne(b1.y) << 16);
  o.w = bf16rne(b1.z) | (bf16rne(b1.w) << 16);
  Bib[i] = o;
}

// ============================================================================
// Persistent kernel. NO agent acquire/release in the loop (no L2 invalidates):
//  - producers: vmcnt-drained (__syncthreads) relaxed-agent stores (sc1,
//    write-through) for x-state + per-block flag; flag value = #steps done.
//  - consumers: wave-0 polls 256 flags with relaxed-agent loads (L2-bypass);
//    control dependency orders the subsequent reads.
//  - x-state ring (RING slots): readers first-touch each slot -> plain cached
//    loads are fresh (slot reuse after 16 steps; Bi stream cycles L2 fully).
//  - Br plane in LDS (swizzled, conflict-free); Bi streamed -> 4 MB/XCD = L2.
// Fragment maps identical to rounds 10-15 (verified, absmax 0.0039).
// ============================================================================
__global__ __launch_bounds__(TPB)
void rnn_persistent(const uint16_t* __restrict__ Brb,
                    const uint16_t* __restrict__ Bib,
                    const float* __restrict__ omega,
                    const float* __restrict__ ang,
                    uint16_t* __restrict__ xring,  // RING * XSZ u16
                    uint32_t* __restrict__ flags,  // 256 * 16 u32, zeroed
                    float* __restrict__ out,
                    int NT) {
  extern __shared__ char smem[];
  uint4* BrL = (uint4*)smem;                       // 16 rows * 512 slots = 128 KB
  float* red = (float*)(smem + 131072);            // 8*16*REDS fp32 = 8704 B

  const int tid  = threadIdx.x;
  const int w    = tid >> 6;       // 0..7, k-window of 512 nodes
  const int lane = tid & 63;
  const int al   = lane & 15;
  const int kq   = lane >> 4;
  const int row0 = blockIdx.x * MROWS;
  const int bid  = blockIdx.x;
  const int p1   = al & 7;
  const int p2   = p1 ^ 1;
  const int swz  = al & 7;
  const uint64_t sm64 = (al & 1) ? 0ull : 0x8000800080008000ull;  // negate -xi (even cols)

  // ---- stage Br slice into LDS, swizzled: phys = row*512 + (u ^ (row&7)) ----
  for (int j = tid; j < MROWS * 512; j += TPB) {
    int row = j >> 9;
    int u   = j & 511;
    uint4 v = *(const uint4*)(Brb + (size_t)(row0 + row) * NN + u * 8);
    BrL[row * 512 + (u ^ (row & 7))] = v;
  }

  // ---- t=0: x0 = exp(i*theta); diag regs; out[0]; ring slot 0 ----
  float myval = 0.f, om = 0.f;
  int bb = 0, mm = 0, ri = 0, cc = 0;
  if (tid < 128) {
    int r = tid >> 3; cc = tid & 7;
    mm = row0 + r; bb = cc >> 1; ri = cc & 1;
    om = omega[bb * NN + mm];
    float sv, cv;
    sincosf(ang[bb * NN + mm], &sv, &cv);
    myval = ri ? sv : cv;
    if (!ri) out[bb * NN + mm] = myval;
    float s2 = __shfl(myval, (lane + 8) & 63, 64);     // partner (r+1, same c)
    if (!((tid >> 3) & 1)) {                            // even r: pack node pair
      uint32_t pk = bf16rne(myval) | (bf16rne(s2) << 16);
      uint32_t* dst = (uint32_t*)xring + ((cc * NN + mm) >> 1);
      __hip_atomic_store(dst, pk, __ATOMIC_RELAXED, __HIP_MEMORY_SCOPE_AGENT);
    }
  }
  __syncthreads();                                     // drain stores + LDS writes
  if (tid == 0)
    __hip_atomic_store(&flags[bid * 16], 1u, __ATOMIC_RELAXED, __HIP_MEMORY_SCOPE_AGENT);

  const int nb = w * 512 + kq * 8;                     // lane's k-window base
  const uint16_t* birow = Bib + (size_t)(row0 + al) * NN + nb;

  for (int t = 1; t < NT; ++t) {
    // ---- wait: all 256 flags >= t (step t-1 data visible) ----
    if (tid < 64) {
      const uint32_t want = (uint32_t)t;
      bool done = false;
      for (int spin = 0; spin < (1 << 22) && !done; ++spin) {
        bool ok = true;
#pragma unroll
        for (int i = 0; i < 4; ++i) {
          uint32_t f = __hip_atomic_load(&flags[(lane * 4 + i) * 16],
                                         __ATOMIC_RELAXED, __HIP_MEMORY_SCOPE_AGENT);
          ok &= (f >= want);
        }
        done = (bool)__all(ok);
        if (!done) __builtin_amdgcn_s_sleep(2);
      }
    }
    __syncthreads();

    const uint16_t* xs = xring + (size_t)((t - 1) & (RING - 1)) * XSZ;
    f32x4 accA = {0.f, 0.f, 0.f, 0.f};
    f32x4 accB = {0.f, 0.f, 0.f, 0.f};

#define SSTEP(S)                                                                \
    { union { uint4 q; bf16x8 v; } fr;                                         \
      fr.q = BrL[al * 512 + (((w << 6) + (S << 2) + kq) ^ swz)];                \
      bf16x8 fi = *(const bf16x8*)(birow + S * 32);                            \
      const uint16_t* x1p = xs + p1 * NN + nb + S * 32;                         \
      const uint16_t* x2p = xs + p2 * NN + nb + S * 32;                         \
      union { uint64_t q[2]; bf16x8 v; } u1, u2;                                \
      u1.q[0] = *(const uint64_t*)(x1p);                                        \
      u1.q[1] = *(const uint64_t*)(x1p + 4);                                    \
      u2.q[0] = *(const uint64_t*)(x2p) ^ sm64;                                 \
      u2.q[1] = *(const uint64_t*)(x2p + 4) ^ sm64;                             \
      accA = __builtin_amdgcn_mfma_f32_16x16x32_bf16(fr.v, u1.v, accA, 0, 0, 0);\
      accB = __builtin_amdgcn_mfma_f32_16x16x32_bf16(fi, u2.v, accB, 0, 0, 0); }
    SSTEP(0)  SSTEP(1)  SSTEP(2)  SSTEP(3)
    SSTEP(4)  SSTEP(5)  SSTEP(6)  SSTEP(7)
    SSTEP(8)  SSTEP(9)  SSTEP(10) SSTEP(11)
    SSTEP(12) SSTEP(13) SSTEP(14) SSTEP(15)
#undef SSTEP

    // ---- partial tiles -> padded LDS ----
    {
      float* rw = red + w * 16 * REDS;
      rw[(kq * 4 + 0) * REDS + al] = accA[0] + accB[0];
      rw[(kq * 4 + 1) * REDS + al] = accA[1] + accB[1];
      rw[(kq * 4 + 2) * REDS + al] = accA[2] + accB[2];
      rw[(kq * 4 + 3) * REDS + al] = accA[3] + accB[3];
    }
    __syncthreads();

    // ---- cross-wave sum + diagonal + writes ----
    if (tid < 128) {
      int r = tid >> 3;
      float s = 0.f;
#pragma unroll
      for (int w2 = 0; w2 < 8; ++w2) s += red[w2 * 16 * REDS + r * REDS + cc];
      float other = __shfl_xor(myval, 1, 64);
      float xr = ri ? other : myval;
      float xi = ri ? myval : other;
      // i*omega*(xr + i*xi) = -omega*xi + i*omega*xr
      s += ri ? (om * xr) : (-om * xi);
      myval = s;                                       // fp32 diag chain in reg
      if (!ri) out[(size_t)t * (BB * NN) + bb * NN + mm] = s;
      float s2 = __shfl(s, (lane + 8) & 63, 64);       // partner (r+1, same c)
      if (!((tid >> 3) & 1)) {
        uint32_t pk = bf16rne(s) | (bf16rne(s2) << 16);
        uint32_t* dst = (uint32_t*)(xring + (size_t)(t & (RING - 1)) * XSZ)
                        + ((cc * NN + mm) >> 1);
        __hip_atomic_store(dst, pk, __ATOMIC_RELAXED, __HIP_MEMORY_SCOPE_AGENT);
      }
    }
    __syncthreads();                                   // drain x stores (vmcnt 0)
    if (tid == 0)
      __hip_atomic_store(&flags[bid * 16], (uint32_t)(t + 1),
                         __ATOMIC_RELAXED, __HIP_MEMORY_SCOPE_AGENT);
  }
}

// ============================================================================
// Fallback (fp32 B direct, per-step launches) — only if coop launch fails.
// ============================================================================
__global__ void init_kernel(const float* __restrict__ ang,
                            float2* __restrict__ st0, float* __restrict__ out0) {
  int i = blockIdx.x * blockDim.x + threadIdx.x;
  if (i < BB * NN) {
    float s, c;
    sincosf(ang[i], &s, &c);
    st0[i] = make_float2(c, s);
    out0[i] = c;
  }
}

__global__ __launch_bounds__(1024)
void step_fb(const float* __restrict__ Brf, const float* __restrict__ Bif,
             const float* __restrict__ omega,
             const float2* __restrict__ stPrev, float2* __restrict__ stNext,
             float* __restrict__ outRe) {
  extern __shared__ float lds[];
  float* xl  = lds;
  float* xh  = lds + NN * 4;
  float* red = lds + NN * 8;
  const int tid = threadIdx.x;
#pragma unroll
  for (int k = 0; k < 8; ++k) {
    int idx = tid + k * 1024;
    int half = idx >> 12;
    int n = idx & (NN - 1);
    float2 v0 = stPrev[(half * 2) * NN + n];
    float2 v1 = stPrev[(half * 2 + 1) * NN + n];
    reinterpret_cast<float4*>(half ? xh : xl)[n] = make_float4(v0.x, v0.y, v1.x, v1.y);
  }
  __syncthreads();
  const int w = tid >> 6, lane = tid & 63, rg = w >> 2, q = w & 3;
  const int row0 = blockIdx.x * MROWS + rg * 4;
  float acc[4][8];
#pragma unroll
  for (int r = 0; r < 4; ++r)
#pragma unroll
    for (int c = 0; c < 8; ++c) acc[r][c] = 0.0f;
#define CFMA(A, BR, BI, XA, XB)                                   \
  A[0] = fmaf(BR, XA.x, A[0]); A[0] = fmaf(-BI, XA.y, A[0]);      \
  A[1] = fmaf(BR, XA.y, A[1]); A[1] = fmaf(BI, XA.x, A[1]);       \
  A[2] = fmaf(BR, XA.z, A[2]); A[2] = fmaf(-BI, XA.w, A[2]);      \
  A[3] = fmaf(BR, XA.w, A[3]); A[3] = fmaf(BI, XA.z, A[3]);       \
  A[4] = fmaf(BR, XB.x, A[4]); A[4] = fmaf(-BI, XB.y, A[4]);      \
  A[5] = fmaf(BR, XB.y, A[5]); A[5] = fmaf(BI, XB.x, A[5]);       \
  A[6] = fmaf(BR, XB.z, A[6]); A[6] = fmaf(-BI, XB.w, A[6]);      \
  A[7] = fmaf(BR, XB.w, A[7]); A[7] = fmaf(BI, XB.z, A[7]);
  for (int i4 = 0; i4 < 4; ++i4) {
    const int n0 = q * 1024 + i4 * 256 + lane * 4;
    float4 xa[4], xb[4];
#pragma unroll
    for (int j = 0; j < 4; ++j) {
      xa[j] = reinterpret_cast<const float4*>(xl)[n0 + j];
      xb[j] = reinterpret_cast<const float4*>(xh)[n0 + j];
    }
#pragma unroll
    for (int r = 0; r < 4; ++r) {
      const float4 pvr = reinterpret_cast<const float4*>(Brf + (size_t)(row0 + r) * NN)[q * 256 + i4 * 64 + lane];
      const float4 pvi = reinterpret_cast<const float4*>(Bif + (size_t)(row0 + r) * NN)[q * 256 + i4 * 64 + lane];
      float* a = acc[r];
      CFMA(a, pvr.x, pvi.x, xa[0], xb[0]);
      CFMA(a, pvr.y, pvi.y, xa[1], xb[1]);
      CFMA(a, pvr.z, pvi.z, xa[2], xb[2]);
      CFMA(a, pvr.w, pvi.w, xa[3], xb[3]);
    }
  }
#undef CFMA
  float t0 = acc[0][0], t1 = acc[0][1], t2 = acc[0][2], t3 = acc[0][3];
  float t4 = acc[0][4], t5 = acc[0][5], t6 = acc[0][6], t7 = acc[0][7];
  float t8 = acc[1][0], t9 = acc[1][1], t10 = acc[1][2], t11 = acc[1][3];
  float t12 = acc[1][4], t13 = acc[1][5], t14 = acc[1][6], t15 = acc[1][7];
  float t16 = acc[2][0], t17 = acc[2][1], t18 = acc[2][2], t19 = acc[2][3];
  float t20 = acc[2][4], t21 = acc[2][5], t22 = acc[2][6], t23 = acc[2][7];
  float t24 = acc[3][0], t25 = acc[3][1], t26 = acc[3][2], t27 = acc[3][3];
  float t28 = acc[3][4], t29 = acc[3][5], t30 = acc[3][6], t31 = acc[3][7];
#define RSTEP(LO, HI, M)                                          \
  { float s_ = up ? LO : HI;                                      \
    s_ = __shfl_xor(s_, M, 64);                                   \
    LO = (up ? HI : LO) + s_; }
  { const bool up = (lane & 32) != 0;
    RSTEP(t0, t16, 32)  RSTEP(t1, t17, 32)  RSTEP(t2, t18, 32)  RSTEP(t3, t19, 32)
    RSTEP(t4, t20, 32)  RSTEP(t5, t21, 32)  RSTEP(t6, t22, 32)  RSTEP(t7, t23, 32)
    RSTEP(t8, t24, 32)  RSTEP(t9, t25, 32)  RSTEP(t10, t26, 32) RSTEP(t11, t27, 32)
    RSTEP(t12, t28, 32) RSTEP(t13, t29, 32) RSTEP(t14, t30, 32) RSTEP(t15, t31, 32) }
  { const bool up = (lane & 16) != 0;
    RSTEP(t0, t8, 16)  RSTEP(t1, t9, 16)  RSTEP(t2, t10, 16) RSTEP(t3, t11, 16)
    RSTEP(t4, t12, 16) RSTEP(t5, t13, 16) RSTEP(t6, t14, 16) RSTEP(t7, t15, 16) }
  { const bool up = (lane & 8) != 0;
    RSTEP(t0, t4, 8) RSTEP(t1, t5, 8) RSTEP(t2, t6, 8) RSTEP(t3, t7, 8) }
  { const bool up = (lane & 4) != 0;
    RSTEP(t0, t2, 4) RSTEP(t1, t3, 4) }
  { const bool up = (lane & 2) != 0;
    RSTEP(t0, t1, 2) }
#undef RSTEP
  t0 += __shfl_xor(t0, 1, 64);
  if (!(lane & 1)) red[w * 32 + ((lane >> 1) & 31)] = t0;
  __syncthreads();
  if (tid < 128) {
    int rg2 = tid >> 5, v = tid & 31;
    float s = red[(rg2 * 4 + 0) * 32 + v] + red[(rg2 * 4 + 1) * 32 + v] +
              red[(rg2 * 4 + 2) * 32 + v] + red[(rg2 * 4 + 3) * 32 + v];
    int r = v >> 3, c = v & 7, b = c >> 1, ri = c & 1;
    int m = blockIdx.x * MROWS + rg2 * 4 + r;
    float om = omega[b * NN + m];
    const float* xs = (b < 2) ? xl : xh;
    float xr = xs[m * 4 + (b & 1) * 2];
    float xi = xs[m * 4 + (b & 1) * 2 + 1];
    s += (ri == 0) ? (-om * xi) : (om * xr);
    reinterpret_cast<float*>(stNext)[(b * NN + m) * 2 + ri] = s;
    if (ri == 0) outRe[b * NN + m] = s;
  }
}

// ---------- host ----------
extern "C" void kernel_launch(void* const* d_in, const int* in_sizes, int n_in,
                              void* d_out, int out_size, void* d_ws, size_t ws_size,
                              hipStream_t stream) {
  const float* B_real = (const float*)d_in[0];
  const float* B_imag = (const float*)d_in[1];
  const float* omega  = (const float*)d_in[2];
  const float* ang    = (const float*)d_in[3];
  float* out = (float*)d_out;

  int NT = out_size / (BB * NN);                                 // 256
  const size_t planeBytes = (size_t)NN * NN * 2;                 // 32 MB
  const size_t xringBytes = (size_t)RING * XSZ * 2;              // 2 MB
  const size_t flagBytes  = 256 * 16 * sizeof(uint32_t);         // 16 KB
  const bool coop = ws_size >= 2 * planeBytes + xringBytes + flagBytes;

  hipError_t launched = hipErrorUnknown;
  if (coop) {
    uint16_t* Brb   = (uint16_t*)d_ws;
    uint16_t* Bib   = Brb + (size_t)NN * NN;
    uint16_t* xring = (uint16_t*)((char*)d_ws + 2 * planeBytes);
    uint32_t* flags = (uint32_t*)((char*)d_ws + 2 * planeBytes + xringBytes);

    (void)hipMemsetAsync((void*)flags, 0, flagBytes, stream);    // flags -> 0
    pack_planes<<<NN * NN / 8 / 256, 256, 0, stream>>>(B_real, B_imag,
                                                       (uint4*)Brb, (uint4*)Bib);

    const size_t shmem = 131072 + (size_t)8 * 16 * REDS * 4;     // 139776 B
    (void)hipFuncSetAttribute((const void*)&rnn_persistent,
                              hipFuncAttributeMaxDynamicSharedMemorySize, (int)shmem);

    void* kargs[8];
    kargs[0] = (void*)&Brb;
    kargs[1] = (void*)&Bib;
    kargs[2] = (void*)&omega;
    kargs[3] = (void*)&ang;
    kargs[4] = (void*)&xring;
    kargs[5] = (void*)&flags;
    kargs[6] = (void*)&out;
    kargs[7] = (void*)&NT;
    launched = hipLaunchCooperativeKernel((const void*)&rnn_persistent,
                                          dim3(NBLK), dim3(TPB),
                                          kargs, (unsigned int)shmem, stream);
  }

  if (launched != hipSuccess) {
    // fallback: per-step launches, fp32 B from inputs, state ping-pong in ws
    float2* st0 = (float2*)d_ws;
    float2* st1 = st0 + BB * NN;
    const size_t shmemF = (size_t)(NN * 8 + 16 * 32) * sizeof(float);
    (void)hipFuncSetAttribute((const void*)&step_fb,
                              hipFuncAttributeMaxDynamicSharedMemorySize, (int)shmemF);
    init_kernel<<<(BB * NN + 255) / 256, 256, 0, stream>>>(ang, st0, out);
    for (int t = 1; t < NT; ++t) {
      float2* sp = ((t - 1) & 1) ? st1 : st0;
      float2* sn = (t & 1) ? st1 : st0;
      float* outT = out + (size_t)t * BB * NN;
      step_fb<<<NN / MROWS, 1024, shmemF, stream>>>(B_real, B_imag, omega, sp, sn, outT);
    }
  }
}